// Round 6
// baseline (13040.691 us; speedup 1.0000x reference)
//
#include <hip/hip_runtime.h>

#define SEQ   1024
#define TLEN  1024
#define NB_B  4          // batches per block
#define NBLK  128        // 128*4 = 512 merged batches (256 X1 + 256 X2)
#define NTHR  512
#define SLICE 3072       // floats per output batch-slice: 1024*3

// Transposed-weight float offsets INSIDE d_out (consumed before mlp2 writes)
#define WT0IH 0          // [16][512][4] from Wih0[512][64]
#define WT0HH 32768      // [32][512][4] from Whh0[512][128]
#define WT1IH 98304      // [32][512][4] from Wih1[512][128]
#define WT1HH 163840     // [32][512][4] from Whh1[512][128]
#define WTOT  229376
// Final-h vector v (0..511) lives at out[(96+(v>>2))*SLICE + 1024 + (v&3)*128 + u]
// (slices 96..223, offset range [1024,1536) — disjoint from weights and base writes)

__device__ __forceinline__ float sig1(float x)  { return 1.0f / (1.0f + __expf(-x)); }
__device__ __forceinline__ float tanh1(float x) { return 1.0f - 2.0f / (__expf(2.0f * x) + 1.0f); }

// One-time weight transpose: [row][k] -> [k>>2][row][k&3], into d_out[0..WTOT)
extern "C" __global__ void __launch_bounds__(256)
prep_t(const float* __restrict__ Wih0, const float* __restrict__ Whh0,
       const float* __restrict__ Wih1, const float* __restrict__ Whh1,
       float* __restrict__ wt) {
  const int idx = blockIdx.x * 256 + threadIdx.x;
  if (idx >= WTOT) return;
  float v; int r, k, base;
  if (idx < 32768)      { r = idx >> 6;  k = idx & 63;                  v = Wih0[idx]; base = WT0IH; }
  else if (idx < 98304) { int j = idx - 32768;  r = j >> 7; k = j & 127; v = Whh0[j];  base = WT0HH; }
  else if (idx < 163840){ int j = idx - 98304;  r = j >> 7; k = j & 127; v = Wih1[j];  base = WT1IH; }
  else                  { int j = idx - 163840; r = j >> 7; k = j & 127; v = Whh1[j];  base = WT1HH; }
  wt[base + (((k >> 2) * 512 + r) << 2) + (k & 3)] = v;
}

// Block-local 2-layer LSTM over NB_B batches; zero inter-block traffic.
// wt/hout alias d_out (disjoint regions) -> no __restrict__ on them.
extern "C" __global__ void __launch_bounds__(NTHR)
lstm_nb(const float* __restrict__ X1, const float* __restrict__ X2,
        const float* __restrict__ W1m, const float* __restrict__ b1m,
        const float* __restrict__ bih0, const float* __restrict__ bhh0,
        const float* __restrict__ bih1, const float* __restrict__ bhh1,
        const float* wt, float* hout) {
  __shared__ float hbuf[NB_B * 320];   // per batch: feat[64] | h0[128] | h1[128]
  __shared__ float gacc[512 * NB_B];   // [gate-row][batch]
  __shared__ float xS[NB_B * 5];

  const int tid = threadIdx.x;
  const int blk = blockIdx.x;
  const int r   = tid;                 // gate row 0..511 (g*128+u)
  const int m   = tid & 63;            // mlp1 unit
  const int bf  = tid >> 6;            // mlp1 batch slot (active if < NB_B)
  const int u   = tid & 127;           // hidden unit
  const int bp  = tid >> 7;            // update batch 0..3

  float w1r[5];
  #pragma unroll
  for (int i = 0; i < 5; ++i) w1r[i] = W1m[m * 5 + i];
  const float b1r   = b1m[m];
  const float bias0 = bih0[r] + bhh0[r];
  const float bias1 = bih1[r] + bhh1[r];

  const int b5 = (tid < NB_B * 5) ? tid / 5 : 0;
  const int c5 = tid - b5 * 5;
  const int ebx = blk * NB_B + b5;
  const float* xsrc = (ebx < 256) ? (X1 + (size_t)ebx * SEQ * 5 + c5)
                                  : (X2 + (size_t)(ebx - 256) * SEQ * 5 + c5);

  float c0 = 0.0f, c1 = 0.0f;
  for (int i = tid; i < NB_B * 320; i += NTHR) hbuf[i] = 0.0f;
  __syncthreads();

  const float4* wih0 = (const float4*)(wt + WT0IH) + r;  // [kc][512] float4s
  const float4* whh0 = (const float4*)(wt + WT0HH) + r;
  const float4* wih1 = (const float4*)(wt + WT1IH) + r;
  const float4* whh1 = (const float4*)(wt + WT1HH) + r;

  for (int t = 0; t < SEQ; ++t) {
    if (tid < NB_B * 5) xS[tid] = xsrc[(size_t)t * 5];
    __syncthreads();

    // mlp1: feat[t]
    if (bf < NB_B) {
      const float* xb = &xS[bf * 5];
      float s = b1r;
      #pragma unroll
      for (int i = 0; i < 5; ++i) s += w1r[i] * xb[i];
      hbuf[bf * 320 + m] = fmaxf(s, 0.0f);
    }
    __syncthreads();

    // layer0 gate rows: Wih0.feat + Whh0.h0[t-1]
    {
      float acc[NB_B];
      #pragma unroll
      for (int b = 0; b < NB_B; ++b) acc[b] = bias0;
      #pragma unroll 4
      for (int kc = 0; kc < 16; ++kc) {
        float4 wv = wih0[kc * 512];
        #pragma unroll
        for (int b = 0; b < NB_B; ++b) {
          float4 hv = *(const float4*)&hbuf[b * 320 + kc * 4];
          acc[b] += wv.x * hv.x; acc[b] += wv.y * hv.y;
          acc[b] += wv.z * hv.z; acc[b] += wv.w * hv.w;
        }
      }
      #pragma unroll 4
      for (int kc = 0; kc < 32; ++kc) {
        float4 wv = whh0[kc * 512];
        #pragma unroll
        for (int b = 0; b < NB_B; ++b) {
          float4 hv = *(const float4*)&hbuf[b * 320 + 64 + kc * 4];
          acc[b] += wv.x * hv.x; acc[b] += wv.y * hv.y;
          acc[b] += wv.z * hv.z; acc[b] += wv.w * hv.w;
        }
      }
      *(float4*)&gacc[r * NB_B] = make_float4(acc[0], acc[1], acc[2], acc[3]);
    }
    __syncthreads();

    // layer0 state update -> h0[t]
    {
      float gi = gacc[(u)       * NB_B + bp];
      float gf = gacc[(128 + u) * NB_B + bp];
      float gg = gacc[(256 + u) * NB_B + bp];
      float go = gacc[(384 + u) * NB_B + bp];
      float cc = sig1(gf) * c0 + sig1(gi) * tanh1(gg);
      c0 = cc;
      hbuf[bp * 320 + 64 + u] = sig1(go) * tanh1(cc);
    }
    __syncthreads();

    // layer1 gate rows: Wih1.h0[t] + Whh1.h1[t-1]
    {
      float acc[NB_B];
      #pragma unroll
      for (int b = 0; b < NB_B; ++b) acc[b] = bias1;
      #pragma unroll 4
      for (int kc = 0; kc < 32; ++kc) {
        float4 wv = wih1[kc * 512];
        #pragma unroll
        for (int b = 0; b < NB_B; ++b) {
          float4 hv = *(const float4*)&hbuf[b * 320 + 64 + kc * 4];
          acc[b] += wv.x * hv.x; acc[b] += wv.y * hv.y;
          acc[b] += wv.z * hv.z; acc[b] += wv.w * hv.w;
        }
      }
      #pragma unroll 4
      for (int kc = 0; kc < 32; ++kc) {
        float4 wv = whh1[kc * 512];
        #pragma unroll
        for (int b = 0; b < NB_B; ++b) {
          float4 hv = *(const float4*)&hbuf[b * 320 + 192 + kc * 4];
          acc[b] += wv.x * hv.x; acc[b] += wv.y * hv.y;
          acc[b] += wv.z * hv.z; acc[b] += wv.w * hv.w;
        }
      }
      *(float4*)&gacc[r * NB_B] = make_float4(acc[0], acc[1], acc[2], acc[3]);
    }
    __syncthreads();

    // layer1 state update -> h1[t]; final h -> out-slice stash
    {
      float gi = gacc[(u)       * NB_B + bp];
      float gf = gacc[(128 + u) * NB_B + bp];
      float gg = gacc[(256 + u) * NB_B + bp];
      float go = gacc[(384 + u) * NB_B + bp];
      float cc = sig1(gf) * c1 + sig1(gi) * tanh1(gg);
      c1 = cc;
      float hv = sig1(go) * tanh1(cc);
      hbuf[bp * 320 + 192 + u] = hv;
      if (t == SEQ - 1)
        hout[(size_t)(96 + blk) * SLICE + 1024 + bp * 128 + u] = hv;
    }
    __syncthreads();
  }
}

// base[b][m] = b1[m] + W1[m,0:128].hL[b] + W1[m,128:256].hR[b] -> out[b*SLICE + m]
extern "C" __global__ void __launch_bounds__(128)
mlp2_pre(const float* __restrict__ W1, const float* __restrict__ b1, float* out) {
  __shared__ float inpS[256];
  const int b = blockIdx.x, tid = threadIdx.x;
  inpS[tid]       = out[(size_t)(96  + (b >> 2)) * SLICE + 1024 + (b & 3) * 128 + tid];
  inpS[128 + tid] = out[(size_t)(160 + (b >> 2)) * SLICE + 1024 + (b & 3) * 128 + tid];
  __syncthreads();
  const float* wr = W1 + (size_t)tid * 257;
  float s = b1[tid];
  #pragma unroll 4
  for (int k = 0; k < 256; ++k) s += wr[k] * inpS[k];
  out[(size_t)b * SLICE + tid] = s;
}

// Final: out[b][t][o] = b2[o] + sum_m W2[o][m] * relu(base[b][m] + W1[m][256]*T[b][t])
extern "C" __global__ void __launch_bounds__(256)
mlp2_k(const float* __restrict__ T, const float* __restrict__ W1,
       const float* __restrict__ b2, const float* __restrict__ W2, float* out) {
  __shared__ float baseS[128], w1l[128], w2S[384];
  const int b = blockIdx.x, tid = threadIdx.x;
  if (tid < 128) {
    baseS[tid] = out[(size_t)b * SLICE + tid];   // read own slice BEFORE any write
    w1l[tid]   = W1[(size_t)tid * 257 + 256];
  }
  // FIX (root cause of rounds 0-5): 256 threads must fill ALL 384 w2S entries.
  // Old `if (tid < 384) w2S[tid] = W2[tid];` left w2S[256..383] = stale LDS garbage
  // -> output channel 2 corrupted by launch-varying junk (absmax 0.34-0.63).
  w2S[tid] = W2[tid];
  if (tid < 128) w2S[256 + tid] = W2[256 + tid];
  __syncthreads();
  float x[4];
  #pragma unroll
  for (int q = 0; q < 4; ++q) x[q] = T[(size_t)b * TLEN + tid + q * 256];
  float a0[4], a1[4], a2[4];
  #pragma unroll
  for (int q = 0; q < 4; ++q) { a0[q] = b2[0]; a1[q] = b2[1]; a2[q] = b2[2]; }
  for (int mm = 0; mm < 128; ++mm) {
    float bm = baseS[mm], wl = w1l[mm];
    float w20 = w2S[mm], w21 = w2S[128 + mm], w22 = w2S[256 + mm];
    #pragma unroll
    for (int q = 0; q < 4; ++q) {
      float hv = fmaxf(bm + wl * x[q], 0.0f);
      a0[q] += w20 * hv; a1[q] += w21 * hv; a2[q] += w22 * hv;
    }
  }
  #pragma unroll
  for (int q = 0; q < 4; ++q) {
    float* o = out + ((size_t)b * TLEN + tid + q * 256) * 3;
    o[0] = a0[q]; o[1] = a1[q]; o[2] = a2[q];
  }
}

extern "C" void kernel_launch(void* const* d_in, const int* in_sizes, int n_in,
                              void* d_out, int out_size, void* d_ws, size_t ws_size,
                              hipStream_t stream) {
  (void)in_sizes; (void)n_in; (void)out_size; (void)d_ws; (void)ws_size;
  const float* X1   = (const float*)d_in[0];
  const float* X2   = (const float*)d_in[1];
  const float* T    = (const float*)d_in[2];
  const float* W1m  = (const float*)d_in[3];
  const float* b1m  = (const float*)d_in[4];
  const float* Wih0 = (const float*)d_in[5];
  const float* Whh0 = (const float*)d_in[6];
  const float* bih0 = (const float*)d_in[7];
  const float* bhh0 = (const float*)d_in[8];
  const float* Wih1 = (const float*)d_in[9];
  const float* Whh1 = (const float*)d_in[10];
  const float* bih1 = (const float*)d_in[11];
  const float* bhh1 = (const float*)d_in[12];
  const float* W1p  = (const float*)d_in[13];
  const float* b1p  = (const float*)d_in[14];
  const float* W2p  = (const float*)d_in[15];
  const float* b2p  = (const float*)d_in[16];

  float* out = (float*)d_out;

  prep_t<<<dim3(896), dim3(256), 0, stream>>>(Wih0, Whh0, Wih1, Whh1, out);
  lstm_nb<<<dim3(NBLK), dim3(NTHR), 0, stream>>>(X1, X2, W1m, b1m,
                                                 bih0, bhh0, bih1, bhh1, out, out);
  mlp2_pre<<<dim3(256), dim3(128), 0, stream>>>(W1p, b1p, out);
  mlp2_k<<<dim3(256), dim3(256), 0, stream>>>(T, W1p, b2p, W2p, out);
}